// Round 5
// baseline (1062.666 us; speedup 1.0000x reference)
//
#include <hip/hip_runtime.h>
#include <hip/hip_bf16.h>

typedef __bf16 bf16x8 __attribute__((ext_vector_type(8)));
typedef float  f32x16 __attribute__((ext_vector_type(16)));

#define NLAYERS 19
#define BROWS   (1u << 20)
#define NPAIRS  (BROWS / 64)      // 16384 pairs of 32-row tiles
#define NBLOCKS 512               // 2 blocks/CU (2*80896 B LDS fits 160 KiB)
#define TPB     1024
#define NWAVES  (NBLOCKS * (TPB / 64))   // 8192 waves -> 2 pairs/wave

// ---- helpers ------------------------------------------------------------

// feature relabeling: swap bits 2 and 3 (self-inverse bijection on 0..31)
__device__ __forceinline__ int phi(int m) {
    return (m & ~12) | ((m & 4) << 1) | ((m & 8) >> 1);
}

// pack bf16(trunc(a)) into low16, bf16(trunc(b)) into high16 (one v_perm_b32)
__device__ __forceinline__ unsigned pack_hi(float a, float b) {
    return __builtin_amdgcn_perm(__float_as_uint(b), __float_as_uint(a), 0x07060302u);
}

// f32 value of the bf16-truncation of v (exact)
__device__ __forceinline__ float trunc_bf16_f32(float v) {
    return __uint_as_float(__float_as_uint(v) & 0xFFFF0000u);
}

__device__ __forceinline__ unsigned cvt_pk_bf16(float a, float b) {
    unsigned r;
    asm("v_cvt_pk_bf16_f32 %0, %1, %2" : "=v"(r) : "v"(a), "v"(b));
    return r;
}

__device__ __forceinline__ float fast_rcp(float a) {
    float r;
    asm("v_rcp_f32 %0, %1" : "=v"(r) : "v"(a));
    return r;
}

__device__ __forceinline__ unsigned short bf16_rne_bits(float f) {
    __hip_bfloat16 b = __float2bfloat16(f);
    return *reinterpret_cast<unsigned short*>(&b);
}

// MFMA forced into arch-VGPR form (no AGPR accvgpr churn).
// init: D != C (C = shared bias fragment, stays live) — early-clobber keeps
// D disjoint from all sources.
__device__ __forceinline__ f32x16 mfma_init(bf16x8 a, bf16x8 b, const f32x16& cb) {
    f32x16 d;
    asm("v_mfma_f32_32x32x16_bf16 %0, %1, %2, %3"
        : "=&v"(d) : "v"(a), "v"(b), "v"(cb));
    return d;
}
// accumulate: D == C in place (the designed MFMA chaining form)
__device__ __forceinline__ void mfma_acc(bf16x8 a, bf16x8 b, f32x16& c) {
    asm("v_mfma_f32_32x32x16_bf16 %0, %1, %2, %0"
        : "+v"(c) : "v"(a), "v"(b));
}

union FragU { unsigned u[4]; bf16x8 v; };

// softsign 16 accumulator values -> sv[]
__device__ __forceinline__ void softsign16(const f32x16& c, float* sv) {
#pragma unroll
    for (int r = 0; r < 16; ++r) {
        float v = c[r];
        sv[r] = v * fast_rcp(1.0f + __builtin_fabsf(v));
    }
}

// Zero-shuffle repack (phi-relabeled weights): B step s elem e = sv[8s+e].
// Purely lane-local: 8 perms + 16 and + 16 sub + 8 cvt_pk, no cross-lane ops.
__device__ __forceinline__ void repack2(const float* sv, bf16x8* bhi, bf16x8* blo) {
#pragma unroll
    for (int s = 0; s < 2; ++s) {
        const float* p = sv + 8 * s;
        FragU H, L;
#pragma unroll
        for (int j = 0; j < 4; ++j) {
            H.u[j] = pack_hi(p[2 * j], p[2 * j + 1]);
            L.u[j] = cvt_pk_bf16(p[2 * j]     - trunc_bf16_f32(p[2 * j]),
                                 p[2 * j + 1] - trunc_bf16_f32(p[2 * j + 1]));
        }
        bhi[s] = H.v; blo[s] = L.v;
    }
}

// build fc1 B fragment (hi/lo) from a 6-float input row (only h=0, e<6 nonzero)
__device__ __forceinline__ void build_x_frag(const float* xp, unsigned hm,
                                             bf16x8& bh, bf16x8& bl) {
    const float2* xr = (const float2*)xp;
    float2 xa = xr[0], xb = xr[1], xc = xr[2];
    FragU BH, BL;
    BH.u[0] = pack_hi(xa.x, xa.y) & hm;
    BH.u[1] = pack_hi(xb.x, xb.y) & hm;
    BH.u[2] = pack_hi(xc.x, xc.y) & hm;
    BH.u[3] = 0u;
    BL.u[0] = cvt_pk_bf16(xa.x - trunc_bf16_f32(xa.x), xa.y - trunc_bf16_f32(xa.y)) & hm;
    BL.u[1] = cvt_pk_bf16(xb.x - trunc_bf16_f32(xb.x), xb.y - trunc_bf16_f32(xb.y)) & hm;
    BL.u[2] = cvt_pk_bf16(xc.x - trunc_bf16_f32(xc.x), xc.y - trunc_bf16_f32(xc.y)) & hm;
    BL.u[3] = 0u;
    bh = BH.v; bl = BL.v;
}

// ---- kernel -------------------------------------------------------------

extern "C" __global__ void __launch_bounds__(TPB, 8)
actuatornet_kernel(const float* __restrict__ x,  const float* __restrict__ W1,
                   const float* __restrict__ b1, const float* __restrict__ Wh,
                   const float* __restrict__ bh, const float* __restrict__ Wout,
                   const float* __restrict__ bout, float* __restrict__ out)
{
    __shared__ alignas(16) unsigned short s_wa_hi[NLAYERS * 2 * 64 * 8];   // 38912 B
    __shared__ alignas(16) unsigned short s_wa_lo[NLAYERS * 2 * 64 * 8];   // 38912 B
    __shared__ alignas(64) float s_bias[NLAYERS * 32];   // [lay][h][16] frag order (phi'd)
    __shared__ alignas(64) float s_b1a[32];              // [h][16] frag order (phi'd)
    __shared__ alignas(64) float s_woa[32];              // [h][16] frag order (phi'd)

    const int tid = threadIdx.x;

    // ---- weight prep: split fp32 -> bf16 hi/lo in MFMA A-fragment order ----
    // A[m][k]: logical out = phi(m) (row relabel), logical in = k (identity).
    for (int idx = tid; idx < NLAYERS * 2 * 64 * 8; idx += TPB) {
        int e = idx & 7, l = (idx >> 3) & 63, s = (idx >> 9) & 1, lay = idx >> 10;
        int fi = 16 * s + 8 * (l >> 5) + e;
        int fo = phi(l & 31);
        float w = Wh[lay * 1024 + fi * 32 + fo];
        unsigned wb = __float_as_uint(w);
        s_wa_hi[idx] = (unsigned short)(wb >> 16);
        s_wa_lo[idx] = bf16_rne_bits(w - __uint_as_float(wb & 0xFFFF0000u));
    }
    // biases / Wout in C/D fragment order with phi: [lay*32 + h*16 + r] =
    // vec[phi((r&3)+8*(r>>2)+4h)]
    for (int idx = tid; idx < NLAYERS * 32; idx += TPB) {
        int r = idx & 15, h2 = (idx >> 4) & 1, lay = idx >> 5;
        int f = (r & 3) + 8 * (r >> 2) + 4 * h2;
        s_bias[idx] = bh[lay * 32 + phi(f)];
    }
    if (tid < 32) {
        int r = tid & 15, h2 = tid >> 4;
        int f = (r & 3) + 8 * (r >> 2) + 4 * h2;
        s_b1a[tid] = b1[phi(f)];
        s_woa[tid] = Wout[phi(f)];
    }
    const float bout_v = bout[0];

    const int lane = tid & 63;
    const int col  = lane & 31;       // batch column within tile
    const int h    = lane >> 5;       // lane half
    const int wid  = blockIdx.x * (TPB / 64) + (tid >> 6);

    // ---- fc1 A-fragment: gather from global into registers (no LDS) ----
    FragU A1H, A1L;
    {
        float w[8];
        const int fo1 = phi(col);
#pragma unroll
        for (int e = 0; e < 8; ++e) {
            int k = 8 * h + e;
            w[e] = (k < 6) ? W1[k * 32 + fo1] : 0.0f;
        }
#pragma unroll
        for (int j = 0; j < 4; ++j) {
            A1H.u[j] = pack_hi(w[2 * j], w[2 * j + 1]);
            A1L.u[j] = cvt_pk_bf16(w[2 * j]     - trunc_bf16_f32(w[2 * j]),
                                   w[2 * j + 1] - trunc_bf16_f32(w[2 * j + 1]));
        }
    }

    __syncthreads();

    const unsigned short* wa_hi_lane = s_wa_hi + lane * 8;
    const unsigned short* wa_lo_lane = s_wa_lo + lane * 8;
    const unsigned hm = (h == 0) ? 0xFFFFFFFFu : 0u;

    for (int pair = wid; pair < NPAIRS; pair += NWAVES) {
        const int baseA = pair * 64;
        const int baseB = baseA + 32;

        // ---- fc1 for both tiles
        bf16x8 BHa, BLa, BHb, BLb;
        build_x_frag(x + (size_t)(baseA + col) * 6, hm, BHa, BLa);
        build_x_frag(x + (size_t)(baseB + col) * 6, hm, BHb, BLb);

        const f32x16 cb1 = *(const f32x16*)(s_b1a + h * 16);
        f32x16 cA = mfma_init(A1H.v, BHa, cb1);
        mfma_acc(A1H.v, BLa, cA);
        mfma_acc(A1L.v, BHa, cA);
        f32x16 cB = mfma_init(A1H.v, BHb, cb1);
        mfma_acc(A1H.v, BLb, cB);
        mfma_acc(A1L.v, BHb, cB);

        float svA[16], svB[16];
        bf16x8 hA[2], lA[2], hB[2], lB[2];
        softsign16(cA, svA);
        repack2(svA, hA, lA);
        softsign16(cB, svB);
        repack2(svB, hB, lB);

        // ---- 19 hidden layers, 2 independent chains per wave
        for (int lay = 0; lay < NLAYERS; ++lay) {
            const bf16x8 ah0 = *(const bf16x8*)(wa_hi_lane + (lay * 2 + 0) * 512);
            const bf16x8 al0 = *(const bf16x8*)(wa_lo_lane + (lay * 2 + 0) * 512);
            const bf16x8 ah1 = *(const bf16x8*)(wa_hi_lane + (lay * 2 + 1) * 512);
            const bf16x8 al1 = *(const bf16x8*)(wa_lo_lane + (lay * 2 + 1) * 512);
            const f32x16 cb = *(const f32x16*)(s_bias + lay * 32 + h * 16);

            f32x16 nA = mfma_init(ah0, hA[0], cb);   // bias as C operand: free init
            mfma_acc(ah0, lA[0], nA);
            mfma_acc(al0, hA[0], nA);
            mfma_acc(ah1, hA[1], nA);
            mfma_acc(ah1, lA[1], nA);
            mfma_acc(al1, hA[1], nA);

            f32x16 nB = mfma_init(ah0, hB[0], cb);
            mfma_acc(ah0, lB[0], nB);
            mfma_acc(al0, hB[0], nB);
            mfma_acc(ah1, hB[1], nB);
            mfma_acc(ah1, lB[1], nB);
            mfma_acc(al1, hB[1], nB);

            softsign16(nA, svA);
            softsign16(nB, svB);
            if (lay != NLAYERS - 1) {
                repack2(svA, hA, lA);
                repack2(svB, hB, lB);
            }
        }

        // ---- fc6: dot(h, Wout) + bout
        const f32x16 wo = *(const f32x16*)(s_woa + h * 16);
        float dA = 0.0f, dB = 0.0f;
#pragma unroll
        for (int r = 0; r < 16; ++r) { dA += svA[r] * wo[r]; dB += svB[r] * wo[r]; }
        dA += __shfl_xor(dA, 32, 64);
        dB += __shfl_xor(dB, 32, 64);
        if (h == 0) {
            out[baseA + col] = dA + bout_v;
            out[baseB + col] = dB + bout_v;
        }
    }
}

// ---- launch -------------------------------------------------------------

extern "C" void kernel_launch(void* const* d_in, const int* in_sizes, int n_in,
                              void* d_out, int out_size, void* d_ws, size_t ws_size,
                              hipStream_t stream) {
    const float* x    = (const float*)d_in[0];
    const float* W1   = (const float*)d_in[1];
    const float* b1   = (const float*)d_in[2];
    const float* Wh   = (const float*)d_in[3];
    const float* bh   = (const float*)d_in[4];
    const float* Wout = (const float*)d_in[5];
    const float* bout = (const float*)d_in[6];
    float* out = (float*)d_out;

    actuatornet_kernel<<<dim3(NBLOCKS), dim3(TPB), 0, stream>>>(
        x, W1, b1, Wh, bh, Wout, bout, out);
}

// Round 6
// 243.345 us; speedup vs baseline: 4.3669x; 4.3669x over previous
//
#include <hip/hip_runtime.h>
#include <hip/hip_bf16.h>

typedef __bf16 bf16x8 __attribute__((ext_vector_type(8)));
typedef float  f32x16 __attribute__((ext_vector_type(16)));

#define NLAYERS 19
#define BROWS   (1u << 20)
#define NTILES  (BROWS / 32)      // 32768 tiles of 32 rows
#define NBLOCKS 256               // 1 block/CU, 16 waves/CU resident
#define TPB     1024
#define NWAVES  (NBLOCKS * (TPB / 64))   // 4096 waves -> 8 tiles/wave

// ---- helpers ------------------------------------------------------------

// feature relabeling: swap bits 2 and 3 (self-inverse bijection on 0..31).
// Makes C/D-slot r of lane-half h hold exactly next-layer B elem e=r&7 of
// K-step s=r>>3 -> repack becomes lane-local (zero cross-lane shuffles).
__device__ __forceinline__ int phi(int m) {
    return (m & ~12) | ((m & 4) << 1) | ((m & 8) >> 1);
}

// pack bf16(trunc(a)) into low16, bf16(trunc(b)) into high16 (one v_perm_b32)
__device__ __forceinline__ unsigned pack_hi(float a, float b) {
    return __builtin_amdgcn_perm(__float_as_uint(b), __float_as_uint(a), 0x07060302u);
}

// f32 value of the bf16-truncation of v (exact)
__device__ __forceinline__ float trunc_bf16_f32(float v) {
    return __uint_as_float(__float_as_uint(v) & 0xFFFF0000u);
}

__device__ __forceinline__ unsigned cvt_pk_bf16(float a, float b) {
    unsigned r;
    asm("v_cvt_pk_bf16_f32 %0, %1, %2" : "=v"(r) : "v"(a), "v"(b));
    return r;
}

__device__ __forceinline__ float fast_rcp(float a) {
    float r;
    asm("v_rcp_f32 %0, %1" : "=v"(r) : "v"(a));
    return r;
}

__device__ __forceinline__ unsigned short bf16_rne_bits(float f) {
    __hip_bfloat16 b = __float2bfloat16(f);
    return *reinterpret_cast<unsigned short*>(&b);
}

// MFMA forced into arch-VGPR form (no AGPR accvgpr churn).
__device__ __forceinline__ f32x16 mfma_init(bf16x8 a, bf16x8 b, const f32x16& cb) {
    f32x16 d;
    asm("v_mfma_f32_32x32x16_bf16 %0, %1, %2, %3"
        : "=&v"(d) : "v"(a), "v"(b), "v"(cb));
    return d;
}
__device__ __forceinline__ void mfma_acc(bf16x8 a, bf16x8 b, f32x16& c) {
    asm("v_mfma_f32_32x32x16_bf16 %0, %1, %2, %0"
        : "+v"(c) : "v"(a), "v"(b));
}

union FragU { unsigned u[4]; bf16x8 v; };

// softsign 16 accumulator values -> sv[]
__device__ __forceinline__ void softsign16(const f32x16& c, float* sv) {
#pragma unroll
    for (int r = 0; r < 16; ++r) {
        float v = c[r];
        sv[r] = v * fast_rcp(1.0f + __builtin_fabsf(v));
    }
}

// Zero-shuffle repack (phi-relabeled weights): B step s elem e = sv[8s+e].
__device__ __forceinline__ void repack2(const float* sv, bf16x8* bhi, bf16x8* blo) {
#pragma unroll
    for (int s = 0; s < 2; ++s) {
        const float* p = sv + 8 * s;
        FragU H, L;
#pragma unroll
        for (int j = 0; j < 4; ++j) {
            H.u[j] = pack_hi(p[2 * j], p[2 * j + 1]);
            L.u[j] = cvt_pk_bf16(p[2 * j]     - trunc_bf16_f32(p[2 * j]),
                                 p[2 * j + 1] - trunc_bf16_f32(p[2 * j + 1]));
        }
        bhi[s] = H.v; blo[s] = L.v;
    }
}

// build fc1 B fragment (hi/lo) from a 6-float input row (only h=0, e<6 nonzero)
__device__ __forceinline__ void build_x_frag(const float* xp, unsigned hm,
                                             bf16x8& bh, bf16x8& bl) {
    const float2* xr = (const float2*)xp;
    float2 xa = xr[0], xb = xr[1], xc = xr[2];
    FragU BH, BL;
    BH.u[0] = pack_hi(xa.x, xa.y) & hm;
    BH.u[1] = pack_hi(xb.x, xb.y) & hm;
    BH.u[2] = pack_hi(xc.x, xc.y) & hm;
    BH.u[3] = 0u;
    BL.u[0] = cvt_pk_bf16(xa.x - trunc_bf16_f32(xa.x), xa.y - trunc_bf16_f32(xa.y)) & hm;
    BL.u[1] = cvt_pk_bf16(xb.x - trunc_bf16_f32(xb.x), xb.y - trunc_bf16_f32(xb.y)) & hm;
    BL.u[2] = cvt_pk_bf16(xc.x - trunc_bf16_f32(xc.x), xc.y - trunc_bf16_f32(xc.y)) & hm;
    BL.u[3] = 0u;
    bh = BH.v; bl = BL.v;
}

// ---- kernel -------------------------------------------------------------

extern "C" __global__ void __launch_bounds__(TPB, 4)   // 128-VGPR cap: no spill
actuatornet_kernel(const float* __restrict__ x,  const float* __restrict__ W1,
                   const float* __restrict__ b1, const float* __restrict__ Wh,
                   const float* __restrict__ bh, const float* __restrict__ Wout,
                   const float* __restrict__ bout, float* __restrict__ out)
{
    __shared__ alignas(16) unsigned short s_wa_hi[NLAYERS * 2 * 64 * 8];   // 38912 B
    __shared__ alignas(16) unsigned short s_wa_lo[NLAYERS * 2 * 64 * 8];   // 38912 B
    __shared__ alignas(64) float s_bias[NLAYERS * 32];   // [lay][h][16] frag order (phi'd)
    __shared__ alignas(64) float s_b1a[32];              // [h][16] frag order (phi'd)
    __shared__ alignas(64) float s_woa[32];              // [h][16] frag order (phi'd)

    const int tid = threadIdx.x;

    // ---- weight prep: split fp32 -> bf16 hi/lo in MFMA A-fragment order ----
    // A[m][k]: logical out = phi(m) (row relabel), logical in = k (identity).
    for (int idx = tid; idx < NLAYERS * 2 * 64 * 8; idx += TPB) {
        int e = idx & 7, l = (idx >> 3) & 63, s = (idx >> 9) & 1, lay = idx >> 10;
        int fi = 16 * s + 8 * (l >> 5) + e;
        int fo = phi(l & 31);
        float w = Wh[lay * 1024 + fi * 32 + fo];
        unsigned wb = __float_as_uint(w);
        s_wa_hi[idx] = (unsigned short)(wb >> 16);
        s_wa_lo[idx] = bf16_rne_bits(w - __uint_as_float(wb & 0xFFFF0000u));
    }
    // biases / Wout in C/D fragment order with phi
    for (int idx = tid; idx < NLAYERS * 32; idx += TPB) {
        int r = idx & 15, h2 = (idx >> 4) & 1, lay = idx >> 5;
        int f = (r & 3) + 8 * (r >> 2) + 4 * h2;
        s_bias[idx] = bh[lay * 32 + phi(f)];
    }
    if (tid < 32) {
        int r = tid & 15, h2 = tid >> 4;
        int f = (r & 3) + 8 * (r >> 2) + 4 * h2;
        s_b1a[tid] = b1[phi(f)];
        s_woa[tid] = Wout[phi(f)];
    }
    const float bout_v = bout[0];

    const int lane = tid & 63;
    const int col  = lane & 31;       // batch column within tile
    const int h    = lane >> 5;       // lane half
    const int wid  = blockIdx.x * (TPB / 64) + (tid >> 6);

    // ---- fc1 A-fragment: gather from global into registers (no LDS) ----
    FragU A1H, A1L;
    {
        float w[8];
        const int fo1 = phi(col);
#pragma unroll
        for (int e = 0; e < 8; ++e) {
            int k = 8 * h + e;
            w[e] = (k < 6) ? W1[k * 32 + fo1] : 0.0f;
        }
#pragma unroll
        for (int j = 0; j < 4; ++j) {
            A1H.u[j] = pack_hi(w[2 * j], w[2 * j + 1]);
            A1L.u[j] = cvt_pk_bf16(w[2 * j]     - trunc_bf16_f32(w[2 * j]),
                                   w[2 * j + 1] - trunc_bf16_f32(w[2 * j + 1]));
        }
    }

    __syncthreads();

    const unsigned short* wa_hi_lane = s_wa_hi + lane * 8;
    const unsigned short* wa_lo_lane = s_wa_lo + lane * 8;
    const unsigned hm = (h == 0) ? 0xFFFFFFFFu : 0u;

    for (int tile = wid; tile < NTILES; tile += NWAVES) {
        const int base = tile * 32;

        // ---- fc1
        bf16x8 BH, BL;
        build_x_frag(x + (size_t)(base + col) * 6, hm, BH, BL);

        const f32x16 cb1 = *(const f32x16*)(s_b1a + h * 16);
        f32x16 c = mfma_init(A1H.v, BH, cb1);
        mfma_acc(A1H.v, BL, c);
        mfma_acc(A1L.v, BH, c);

        float sv[16];
        bf16x8 hf[2], lf[2];
        softsign16(c, sv);
        repack2(sv, hf, lf);

        // ---- 19 hidden layers
        for (int lay = 0; lay < NLAYERS; ++lay) {
            const bf16x8 ah0 = *(const bf16x8*)(wa_hi_lane + (lay * 2 + 0) * 512);
            const bf16x8 al0 = *(const bf16x8*)(wa_lo_lane + (lay * 2 + 0) * 512);
            const bf16x8 ah1 = *(const bf16x8*)(wa_hi_lane + (lay * 2 + 1) * 512);
            const bf16x8 al1 = *(const bf16x8*)(wa_lo_lane + (lay * 2 + 1) * 512);
            const f32x16 cb = *(const f32x16*)(s_bias + lay * 32 + h * 16);

            f32x16 n = mfma_init(ah0, hf[0], cb);   // bias as C operand: free init
            mfma_acc(ah0, lf[0], n);
            mfma_acc(al0, hf[0], n);
            mfma_acc(ah1, hf[1], n);
            mfma_acc(ah1, lf[1], n);
            mfma_acc(al1, hf[1], n);

            softsign16(n, sv);
            if (lay != NLAYERS - 1) repack2(sv, hf, lf);
        }

        // ---- fc6: dot(h, Wout) + bout
        const f32x16 wo = *(const f32x16*)(s_woa + h * 16);
        float dot = 0.0f;
#pragma unroll
        for (int r = 0; r < 16; ++r) dot += sv[r] * wo[r];
        dot += __shfl_xor(dot, 32, 64);
        if (h == 0) out[base + col] = dot + bout_v;
    }
}

// ---- launch -------------------------------------------------------------

extern "C" void kernel_launch(void* const* d_in, const int* in_sizes, int n_in,
                              void* d_out, int out_size, void* d_ws, size_t ws_size,
                              hipStream_t stream) {
    const float* x    = (const float*)d_in[0];
    const float* W1   = (const float*)d_in[1];
    const float* b1   = (const float*)d_in[2];
    const float* Wh   = (const float*)d_in[3];
    const float* bh   = (const float*)d_in[4];
    const float* Wout = (const float*)d_in[5];
    const float* bout = (const float*)d_in[6];
    float* out = (float*)d_out;

    actuatornet_kernel<<<dim3(NBLOCKS), dim3(TPB), 0, stream>>>(
        x, W1, b1, Wh, bh, Wout, bout, out);
}

// Round 7
// 240.923 us; speedup vs baseline: 4.4108x; 1.0101x over previous
//
#include <hip/hip_runtime.h>
#include <hip/hip_bf16.h>

typedef __bf16 bf16x8 __attribute__((ext_vector_type(8)));
typedef float  f32x16 __attribute__((ext_vector_type(16)));

#define NLAYERS 19
#define BROWS   (1u << 20)
#define NTILES  (BROWS / 32)      // 32768 tiles of 32 rows
#define NBLOCKS 512               // 2 blocks/CU (2*80896 B LDS = 161792 <= 163840)
#define TPB     1024
#define NWAVES  (NBLOCKS * (TPB / 64))   // 8192 waves -> 4 tiles/wave

// ---- helpers ------------------------------------------------------------

// feature relabeling: swap bits 2 and 3 (self-inverse bijection on 0..31).
// Makes C/D-slot r of lane-half h hold exactly next-layer B elem e=r&7 of
// K-step s=r>>3 -> repack becomes lane-local (zero cross-lane shuffles).
__device__ __forceinline__ int phi(int m) {
    return (m & ~12) | ((m & 4) << 1) | ((m & 8) >> 1);
}

// pack bf16(trunc(a)) into low16, bf16(trunc(b)) into high16 (one v_perm_b32)
__device__ __forceinline__ unsigned pack_hi(float a, float b) {
    return __builtin_amdgcn_perm(__float_as_uint(b), __float_as_uint(a), 0x07060302u);
}

// f32 value of the bf16-truncation of v (exact)
__device__ __forceinline__ float trunc_bf16_f32(float v) {
    return __uint_as_float(__float_as_uint(v) & 0xFFFF0000u);
}

__device__ __forceinline__ unsigned cvt_pk_bf16(float a, float b) {
    unsigned r;
    asm("v_cvt_pk_bf16_f32 %0, %1, %2" : "=v"(r) : "v"(a), "v"(b));
    return r;
}

__device__ __forceinline__ float fast_rcp(float a) {
    float r;
    asm("v_rcp_f32 %0, %1" : "=v"(r) : "v"(a));
    return r;
}

__device__ __forceinline__ unsigned short bf16_rne_bits(float f) {
    __hip_bfloat16 b = __float2bfloat16(f);
    return *reinterpret_cast<unsigned short*>(&b);
}

// MFMA forced into arch-VGPR form (no AGPR accvgpr churn).
__device__ __forceinline__ f32x16 mfma_init(bf16x8 a, bf16x8 b, const f32x16& cb) {
    f32x16 d;
    asm("v_mfma_f32_32x32x16_bf16 %0, %1, %2, %3"
        : "=&v"(d) : "v"(a), "v"(b), "v"(cb));
    return d;
}
__device__ __forceinline__ void mfma_acc(bf16x8 a, bf16x8 b, f32x16& c) {
    asm("v_mfma_f32_32x32x16_bf16 %0, %1, %2, %0"
        : "+v"(c) : "v"(a), "v"(b));
}

union FragU { unsigned u[4]; bf16x8 v; };

// softsign 16 accumulator values -> sv[]
__device__ __forceinline__ void softsign16(const f32x16& c, float* sv) {
#pragma unroll
    for (int r = 0; r < 16; ++r) {
        float v = c[r];
        sv[r] = v * fast_rcp(1.0f + __builtin_fabsf(v));
    }
}

// Zero-shuffle repack (phi-relabeled weights): B step s elem e = sv[8s+e].
__device__ __forceinline__ void repack2(const float* sv, bf16x8* bhi, bf16x8* blo) {
#pragma unroll
    for (int s = 0; s < 2; ++s) {
        const float* p = sv + 8 * s;
        FragU H, L;
#pragma unroll
        for (int j = 0; j < 4; ++j) {
            H.u[j] = pack_hi(p[2 * j], p[2 * j + 1]);
            L.u[j] = cvt_pk_bf16(p[2 * j]     - trunc_bf16_f32(p[2 * j]),
                                 p[2 * j + 1] - trunc_bf16_f32(p[2 * j + 1]));
        }
        bhi[s] = H.v; blo[s] = L.v;
    }
}

// build fc1 B fragment (hi/lo) from a 6-float input row (only h=0, e<6 nonzero)
__device__ __forceinline__ void build_x_frag(const float* xp, unsigned hm,
                                             bf16x8& bh, bf16x8& bl) {
    const float2* xr = (const float2*)xp;
    float2 xa = xr[0], xb = xr[1], xc = xr[2];
    FragU BH, BL;
    BH.u[0] = pack_hi(xa.x, xa.y) & hm;
    BH.u[1] = pack_hi(xb.x, xb.y) & hm;
    BH.u[2] = pack_hi(xc.x, xc.y) & hm;
    BH.u[3] = 0u;
    BL.u[0] = cvt_pk_bf16(xa.x - trunc_bf16_f32(xa.x), xa.y - trunc_bf16_f32(xa.y)) & hm;
    BL.u[1] = cvt_pk_bf16(xb.x - trunc_bf16_f32(xb.x), xb.y - trunc_bf16_f32(xb.y)) & hm;
    BL.u[2] = cvt_pk_bf16(xc.x - trunc_bf16_f32(xc.x), xc.y - trunc_bf16_f32(xc.y)) & hm;
    BL.u[3] = 0u;
    bh = BH.v; bl = BL.v;
}

// ---- kernel -------------------------------------------------------------

extern "C" __global__ void __launch_bounds__(TPB, 4)   // 128-VGPR cap: no spill
actuatornet_kernel(const float* __restrict__ x,  const float* __restrict__ W1,
                   const float* __restrict__ b1, const float* __restrict__ Wh,
                   const float* __restrict__ bh, const float* __restrict__ Wout,
                   const float* __restrict__ bout, float* __restrict__ out)
{
    __shared__ alignas(16) unsigned short s_wa_hi[NLAYERS * 2 * 64 * 8];   // 38912 B
    __shared__ alignas(16) unsigned short s_wa_lo[NLAYERS * 2 * 64 * 8];   // 38912 B
    __shared__ alignas(64) float s_bias[NLAYERS * 32];   // [lay][h][16] frag order (phi'd)
    __shared__ alignas(64) float s_b1a[32];              // [h][16] frag order (phi'd)
    __shared__ alignas(64) float s_woa[32];              // [h][16] frag order (phi'd)

    const int tid = threadIdx.x;

    // ---- weight prep: split fp32 -> bf16 hi/lo in MFMA A-fragment order ----
    // A[m][k]: logical out = phi(m) (row relabel), logical in = k (identity).
    for (int idx = tid; idx < NLAYERS * 2 * 64 * 8; idx += TPB) {
        int e = idx & 7, l = (idx >> 3) & 63, s = (idx >> 9) & 1, lay = idx >> 10;
        int fi = 16 * s + 8 * (l >> 5) + e;
        int fo = phi(l & 31);
        float w = Wh[lay * 1024 + fi * 32 + fo];
        unsigned wb = __float_as_uint(w);
        s_wa_hi[idx] = (unsigned short)(wb >> 16);
        s_wa_lo[idx] = bf16_rne_bits(w - __uint_as_float(wb & 0xFFFF0000u));
    }
    // biases / Wout in C/D fragment order with phi
    for (int idx = tid; idx < NLAYERS * 32; idx += TPB) {
        int r = idx & 15, h2 = (idx >> 4) & 1, lay = idx >> 5;
        int f = (r & 3) + 8 * (r >> 2) + 4 * h2;
        s_bias[idx] = bh[lay * 32 + phi(f)];
    }
    if (tid < 32) {
        int r = tid & 15, h2 = tid >> 4;
        int f = (r & 3) + 8 * (r >> 2) + 4 * h2;
        s_b1a[tid] = b1[phi(f)];
        s_woa[tid] = Wout[phi(f)];
    }
    const float bout_v = bout[0];

    const int lane = tid & 63;
    const int col  = lane & 31;       // batch column within tile
    const int h    = lane >> 5;       // lane half
    const int wid  = blockIdx.x * (TPB / 64) + (tid >> 6);

    // ---- fc1 A-fragment: gather from global into registers (no LDS) ----
    FragU A1H, A1L;
    {
        float w[8];
        const int fo1 = phi(col);
#pragma unroll
        for (int e = 0; e < 8; ++e) {
            int k = 8 * h + e;
            w[e] = (k < 6) ? W1[k * 32 + fo1] : 0.0f;
        }
#pragma unroll
        for (int j = 0; j < 4; ++j) {
            A1H.u[j] = pack_hi(w[2 * j], w[2 * j + 1]);
            A1L.u[j] = cvt_pk_bf16(w[2 * j]     - trunc_bf16_f32(w[2 * j]),
                                   w[2 * j + 1] - trunc_bf16_f32(w[2 * j + 1]));
        }
    }

    __syncthreads();

    const unsigned short* wa_hi_lane = s_wa_hi + lane * 8;
    const unsigned short* wa_lo_lane = s_wa_lo + lane * 8;
    const unsigned hm = (h == 0) ? 0xFFFFFFFFu : 0u;

    for (int tile = wid; tile < NTILES; tile += NWAVES) {
        const int base = tile * 32;

        // ---- fc1
        bf16x8 BH, BL;
        build_x_frag(x + (size_t)(base + col) * 6, hm, BH, BL);

        const f32x16 cb1 = *(const f32x16*)(s_b1a + h * 16);
        f32x16 c = mfma_init(A1H.v, BH, cb1);
        mfma_acc(A1H.v, BL, c);
        mfma_acc(A1L.v, BH, c);

        float sv[16];
        bf16x8 hf[2], lf[2];
        softsign16(c, sv);
        repack2(sv, hf, lf);

        // ---- 19 hidden layers
        for (int lay = 0; lay < NLAYERS; ++lay) {
            const bf16x8 ah0 = *(const bf16x8*)(wa_hi_lane + (lay * 2 + 0) * 512);
            const bf16x8 al0 = *(const bf16x8*)(wa_lo_lane + (lay * 2 + 0) * 512);
            const bf16x8 ah1 = *(const bf16x8*)(wa_hi_lane + (lay * 2 + 1) * 512);
            const bf16x8 al1 = *(const bf16x8*)(wa_lo_lane + (lay * 2 + 1) * 512);
            const f32x16 cb = *(const f32x16*)(s_bias + lay * 32 + h * 16);

            f32x16 n = mfma_init(ah0, hf[0], cb);   // bias as C operand: free init
            mfma_acc(ah0, lf[0], n);
            mfma_acc(al0, hf[0], n);
            mfma_acc(ah1, hf[1], n);
            mfma_acc(ah1, lf[1], n);
            mfma_acc(al1, hf[1], n);

            softsign16(n, sv);
            if (lay != NLAYERS - 1) repack2(sv, hf, lf);
        }

        // ---- fc6: dot(h, Wout) + bout
        const f32x16 wo = *(const f32x16*)(s_woa + h * 16);
        float dot = 0.0f;
#pragma unroll
        for (int r = 0; r < 16; ++r) dot += sv[r] * wo[r];
        dot += __shfl_xor(dot, 32, 64);
        if (h == 0) out[base + col] = dot + bout_v;
    }
}

// ---- launch -------------------------------------------------------------

extern "C" void kernel_launch(void* const* d_in, const int* in_sizes, int n_in,
                              void* d_out, int out_size, void* d_ws, size_t ws_size,
                              hipStream_t stream) {
    const float* x    = (const float*)d_in[0];
    const float* W1   = (const float*)d_in[1];
    const float* b1   = (const float*)d_in[2];
    const float* Wh   = (const float*)d_in[3];
    const float* bh   = (const float*)d_in[4];
    const float* Wout = (const float*)d_in[5];
    const float* bout = (const float*)d_in[6];
    float* out = (float*)d_out;

    actuatornet_kernel<<<dim3(NBLOCKS), dim3(TPB), 0, stream>>>(
        x, W1, b1, Wh, bh, Wout, bout, out);
}